// Round 4
// baseline (301.747 us; speedup 1.0000x reference)
//
#include <hip/hip_runtime.h>

// TileWarping: B=4, C=16, H=512, W=960, UP=4 -> out [4, 48, 128, 240] f32.
// R5 design: direct gather with INLINE-ASM-FORCED load batching.
//  - R3/R4 post-mortem: both the source-level two-phase split and
//    sched_barrier(0) were undone by register-pressure-driven sinking
//    (VGPR stayed 36/48; ~2-3 loads in flight per wave; 8.4 B/cyc/CU
//    delivered = pure latency bound; every throughput counter idle).
//  - R5: the 80 loads per thread (4 taps + 1 fea_l per channel, 16
//    channels) are issued as asm volatile global_load_dword with uniform
//    SGPR channel bases + per-lane byte voffsets. asm volatile is order-
//    pinned and its outputs are registers RA MUST keep live -> 80 loads
//    in flight per wave (20 KB), ~15 waves/CU -> ~300 KB in flight/CU.
//  - The compiler's waitcnt pass does NOT track inline-asm loads: the
//    manual s_waitcnt vmcnt(0) before compute is REQUIRED for
//    correctness, followed by sched_barrier(0) so no consumer is
//    hoisted above it (guide rule #18).
//  - Correctness scheme unchanged: tap columns clamped to [0,W) (always
//    legal addresses); out-of-image taps get zero WEIGHT (channel-
//    invariant), so clamped garbage reads contribute nothing.

#define NB 4
#define NC 16
#define NH 512
#define NW 960
#define TH 128
#define TW 240
#define HW (NH * NW)

__global__ __launch_bounds__(320, 4) void tile_warp_kernel(
    const float* __restrict__ tp,   // [B,3,128,240]
    const float* __restrict__ fl,   // [B,16,512,960]
    const float* __restrict__ fr,   // [B,16,512,960]
    float* __restrict__ out)        // [B,48,128,240]
{
    const int u = blockIdx.x * 320 + threadIdx.x;  // column 0..959
    const int Y = blockIdx.y;                      // full-res row 0..511
    const int b = blockIdx.z;                      // batch 0..3
    const int y = Y >> 2, i = Y & 3;
    const int T = u >> 2, j = u & 3;

    // wave-uniform row bases (blockIdx-derived -> compiler keeps in SGPRs)
    const float* frrow = fr + (size_t)(b * NC) * HW + (size_t)Y * NW;
    const float* flrow = fl + (size_t)(b * NC) * HW + (size_t)Y * NW;

    // ---- per-thread setup (identical arithmetic to R1..R4) ----
    const int tpb = (b * 3 * TH + y) * TW + T;
    const float d   = tp[tpb];
    const float dxv = tp[tpb + TH * TW];
    const float dyv = tp[tpb + 2 * TH * TW];
    const float base = d + ((float)i - 1.5f) * dyv + ((float)j - 1.5f) * dxv;
    const float xf  = (float)u - base;             // kk=1 (disp_d = 0)
    const float x0f = floorf(xf);
    const float w1  = xf - x0f;
    const float w0  = 1.0f - w1;
    const int   x0  = (int)x0f;
    const int   p   = x0 - 1;                      // taps at x = p .. p+3

    // per-variant masked weights: wv_kk = m[2-kk]*w0k[kk] + m[3-kk]*w1k[kk]
    float w0k[3], w1k[3];
#pragma unroll
    for (int kk = 0; kk < 3; ++kk) {
        const int xa = p + 2 - kk;                 // g0 tap
        const int xb = p + 3 - kk;                 // g1 tap
        w0k[kk] = (xa >= 0 && xa < NW) ? w0 : 0.0f;
        w1k[kk] = (xb >= 0 && xb < NW) ? w1 : 0.0f;
    }

    // clamped tap columns -> byte voffsets (always-legal addresses)
    const int v0 = 4 * min(max(p    , 0), NW - 1);
    const int v1 = 4 * min(max(p + 1, 0), NW - 1);
    const int v2 = 4 * min(max(p + 2, 0), NW - 1);
    const int v3 = 4 * min(max(p + 3, 0), NW - 1);
    const int vf = 4 * u;

    // ---- phase 1: issue ALL 80 loads via order-pinned inline asm ----
    float t0[NC], t1[NC], t2[NC], t3[NC], flv[NC];
#pragma unroll
    for (int c = 0; c < NC; ++c) {
        const float* frc = frrow + (size_t)c * HW;   // uniform -> SGPR pair
        const float* flc = flrow + (size_t)c * HW;   // uniform -> SGPR pair
        asm volatile("global_load_dword %0, %1, %2"
                     : "=v"(t0[c]) : "v"(v0), "s"(frc));
        asm volatile("global_load_dword %0, %1, %2"
                     : "=v"(t1[c]) : "v"(v1), "s"(frc));
        asm volatile("global_load_dword %0, %1, %2"
                     : "=v"(t2[c]) : "v"(v2), "s"(frc));
        asm volatile("global_load_dword %0, %1, %2"
                     : "=v"(t3[c]) : "v"(v3), "s"(frc));
        asm volatile("global_load_dword %0, %1, %2"
                     : "=v"(flv[c]) : "v"(vf), "s"(flc));
    }

    // Drain: compiler does not track asm loads -> manual wait is REQUIRED.
    asm volatile("s_waitcnt vmcnt(0)" ::: "memory");
    __builtin_amdgcn_sched_barrier(0);

    // ---- phase 2: compute ----
    float acc0 = 0.f, acc1 = 0.f, acc2 = 0.f;
#pragma unroll
    for (int c = 0; c < NC; ++c) {
        const float wv0 = t2[c] * w0k[0] + t3[c] * w1k[0];
        const float wv1 = t1[c] * w0k[1] + t2[c] * w1k[1];
        const float wv2 = t0[c] * w0k[2] + t1[c] * w1k[2];
        acc0 += fabsf(flv[c] - wv0);
        acc1 += fabsf(flv[c] - wv1);
        acc2 += fabsf(flv[c] - wv2);
    }

    // ---- store: ch = kk*16 + i*4 + j ----
    const size_t obase = ((size_t)(b * 48 + i * 4 + j) * TH + y) * TW + T;
    out[obase]                        = acc0;
    out[obase + 16 * (size_t)TH * TW] = acc1;
    out[obase + 32 * (size_t)TH * TW] = acc2;
}

extern "C" void kernel_launch(void* const* d_in, const int* in_sizes, int n_in,
                              void* d_out, int out_size, void* d_ws, size_t ws_size,
                              hipStream_t stream) {
    const float* tp = (const float*)d_in[0];
    const float* fl = (const float*)d_in[1];
    const float* fr = (const float*)d_in[2];
    float* out = (float*)d_out;

    dim3 grid(3, NH, NB);   // 3 segments x 512 rows x 4 batches
    dim3 block(320);        // 5 waves, thread -> one output pixel column
    tile_warp_kernel<<<grid, block, 0, stream>>>(tp, fl, fr, out);
}

// Round 5
// 273.498 us; speedup vs baseline: 1.1033x; 1.1033x over previous
//
#include <hip/hip_runtime.h>

// TileWarping: B=4, C=16, H=512, W=960, UP=4 -> out [4, 48, 128, 240] f32.
// R6 design: R1's LDS-staged full-row structure + T3/T4 counted-vmcnt
// pipeline (raw s_barrier, never vmcnt(0) mid-loop).
//  - R2..R5 post-mortem: register-resident load batching is un-forceable
//    (compiler re-sinks under pressure; VGPR stayed 36..48, perf pinned at
//    ~128us pure-latency-bound with all throughput counters <20%).
//  - R1's flaw was __syncthreads(): compiler emits s_waitcnt vmcnt(0)
//    before s_barrier, draining ALL DMA before any wave proceeds ->
//    per-block serial {drain, compute, drain, compute} at 2 blocks/CU.
//  - R6: 4 chunks x 4 channels. Issue depth 3: chunks c,c+1,c+2 in flight.
//    Per chunk: counted s_waitcnt vmcnt(N) (waits ONLY chunk c) -> raw
//    __builtin_amdgcn_s_barrier() -> sched_barrier(0) -> compute.
//    fea_l is loaded via asm global_load_dword in the SAME counted stream
//    (4/chunk) so vmcnt accounting is exact. tp setup completes before the
//    first counted issue so compiler-inserted waits can't miscount.
//    Issue order per thread: S0 F0 | S1 F1 | S2 F2 | w(10) S3 F3 c0 |
//    w(10) c1 | w(5) c2 | w(0) c3.   (S=1 DMA, F=4 loads)
//  - Single-shot chunk buffers (no reuse) -> no WAR hazards; every wave
//    waits its own vmcnt before each barrier -> post-barrier the chunk is
//    globally complete (m201-verified pattern).
//  - Correctness scheme unchanged from R1: guards +-16 floats, p clamped
//    to [-16, 972], OOB taps get zero WEIGHT (channel-invariant).

#define NB 4
#define NC 16
#define NH 512
#define NW 960
#define TH 128
#define TW 240
#define HW (NH * NW)
#define GUARD 16
#define CCH 4                          // channels per chunk
#define CBUF (2 * GUARD + CCH * NW)    // 3872 floats per chunk buffer

typedef const __attribute__((address_space(1))) unsigned int* gas_u32;
typedef __attribute__((address_space(3))) unsigned int* las_u32;

__device__ __forceinline__ void stage16(const float* g, float* l) {
    __builtin_amdgcn_global_load_lds((gas_u32)g, (las_u32)l, 16, 0, 0);
}

__global__ __launch_bounds__(960, 2) void tile_warp_kernel(
    const float* __restrict__ tp,   // [B,3,128,240]
    const float* __restrict__ fl,   // [B,16,512,960]
    const float* __restrict__ fr,   // [B,16,512,960]
    float* __restrict__ out)        // [B,48,128,240]
{
    const int u = threadIdx.x;      // column 0..959
    const int Y = blockIdx.x;       // 0..511
    const int b = blockIdx.y;       // 0..3
    const int y = Y >> 2, i = Y & 3;
    const int T = u >> 2, j = u & 3;

    __shared__ float smem[4][CBUF];

    const float* frrow = fr + (size_t)(b * NC) * HW + (size_t)Y * NW;
    const float* flrow = fl + (size_t)(b * NC) * HW + (size_t)Y * NW;

    // ---- setup FIRST (tp loads fully retired before counted stream) ----
    const int tpb = (b * 3 * TH + y) * TW + T;
    const float d   = tp[tpb];
    const float dxv = tp[tpb + TH * TW];
    const float dyv = tp[tpb + 2 * TH * TW];
    const float base = d + ((float)i - 1.5f) * dyv + ((float)j - 1.5f) * dxv;
    const float xf  = (float)u - base;            // kk=1 (disp_d = 0)
    const float x0f = floorf(xf);
    const float w1  = xf - x0f;
    const float w0  = 1.0f - w1;
    const int   x0  = (int)x0f;
    const int   p   = x0 - 1;                     // taps at x = p .. p+3
    const int   p_cl = max(min(p, NW + 12), -GUARD);

    float w0k[3], w1k[3];
#pragma unroll
    for (int kk = 0; kk < 3; ++kk) {
        const int xa = p + 2 - kk;                // g0 tap
        const int xb = p + 3 - kk;                // g1 tap
        w0k[kk] = (xa >= 0 && xa < NW) ? w0 : 0.0f;
        w1k[kk] = (xb >= 0 && xb < NW) ? w1 : 0.0f;
    }
    float acc0 = 0.f, acc1 = 0.f, acc2 = 0.f;

    // staging geometry: slot u covers 16B of the chunk's 4x960 image
    const int srow = u / 240;                     // channel within chunk
    const int scol = 4 * (u % 240);               // column
    const int vf   = 4 * u;                       // fea_l byte voffset

#define ISSUE_STAGE(k) \
    stage16(frrow + (size_t)(4 * (k) + srow) * HW + scol, &smem[k][GUARD + 4 * u])

#define ISSUE_FL(k, r0, r1, r2, r3) do {                                         \
    asm volatile("global_load_dword %0, %1, %2"                                  \
                 : "=v"(r0) : "v"(vf), "s"(flrow + (size_t)(4 * (k) + 0) * HW)); \
    asm volatile("global_load_dword %0, %1, %2"                                  \
                 : "=v"(r1) : "v"(vf), "s"(flrow + (size_t)(4 * (k) + 1) * HW)); \
    asm volatile("global_load_dword %0, %1, %2"                                  \
                 : "=v"(r2) : "v"(vf), "s"(flrow + (size_t)(4 * (k) + 2) * HW)); \
    asm volatile("global_load_dword %0, %1, %2"                                  \
                 : "=v"(r3) : "v"(vf), "s"(flrow + (size_t)(4 * (k) + 3) * HW)); \
} while (0)

#define COMPUTE_CH(k, ch, fv) do {                                   \
    const float* L = &smem[k][GUARD + (ch) * NW + p_cl];             \
    const float m0 = L[0], m1 = L[1], m2 = L[2], m3 = L[3];          \
    const float wv0 = m2 * w0k[0] + m3 * w1k[0];                     \
    const float wv1 = m1 * w0k[1] + m2 * w1k[1];                     \
    const float wv2 = m0 * w0k[2] + m1 * w1k[2];                     \
    acc0 += fabsf((fv) - wv0);                                       \
    acc1 += fabsf((fv) - wv1);                                       \
    acc2 += fabsf((fv) - wv2);                                       \
} while (0)

#define WAITV(n) do {                                                \
    asm volatile("s_waitcnt vmcnt(" #n ")" ::: "memory");            \
    __builtin_amdgcn_sched_barrier(0);                               \
} while (0)

    float fA0, fA1, fA2, fA3;   // chunk 0 fea_l
    float fB0, fB1, fB2, fB3;   // chunk 1
    float fC0, fC1, fC2, fC3;   // chunk 2
    float fD0, fD1, fD2, fD3;   // chunk 3

    __builtin_amdgcn_sched_barrier(0);
    // ---- prologue: 3 chunks in flight ----
    ISSUE_STAGE(0); ISSUE_FL(0, fA0, fA1, fA2, fA3);
    __builtin_amdgcn_sched_barrier(0);
    ISSUE_STAGE(1); ISSUE_FL(1, fB0, fB1, fB2, fB3);
    __builtin_amdgcn_sched_barrier(0);
    ISSUE_STAGE(2); ISSUE_FL(2, fC0, fC1, fC2, fC3);
    __builtin_amdgcn_sched_barrier(0);

    // ---- chunk 0: wait S0,F0 only (S1,F1,S2,F2 = 10 stay in flight) ----
    WAITV(10);
    __builtin_amdgcn_s_barrier();
    __builtin_amdgcn_sched_barrier(0);
    ISSUE_STAGE(3); ISSUE_FL(3, fD0, fD1, fD2, fD3);   // depth-3 refill
    __builtin_amdgcn_sched_barrier(0);
    COMPUTE_CH(0, 0, fA0); COMPUTE_CH(0, 1, fA1);
    COMPUTE_CH(0, 2, fA2); COMPUTE_CH(0, 3, fA3);

    // ---- chunk 1: pending S1..F3 = 15 -> wait(10) retires S1,F1 ----
    WAITV(10);
    __builtin_amdgcn_s_barrier();
    __builtin_amdgcn_sched_barrier(0);
    COMPUTE_CH(1, 0, fB0); COMPUTE_CH(1, 1, fB1);
    COMPUTE_CH(1, 2, fB2); COMPUTE_CH(1, 3, fB3);

    // ---- chunk 2: pending S2..F3 = 10 -> wait(5) retires S2,F2 ----
    WAITV(5);
    __builtin_amdgcn_s_barrier();
    __builtin_amdgcn_sched_barrier(0);
    COMPUTE_CH(2, 0, fC0); COMPUTE_CH(2, 1, fC1);
    COMPUTE_CH(2, 2, fC2); COMPUTE_CH(2, 3, fC3);

    // ---- chunk 3: drain ----
    WAITV(0);
    __builtin_amdgcn_s_barrier();
    __builtin_amdgcn_sched_barrier(0);
    COMPUTE_CH(3, 0, fD0); COMPUTE_CH(3, 1, fD1);
    COMPUTE_CH(3, 2, fD2); COMPUTE_CH(3, 3, fD3);

    // ---- store: ch = kk*16 + i*4 + j ----
    const size_t obase = ((size_t)(b * 48 + i * 4 + j) * TH + y) * TW + T;
    out[obase]                        = acc0;
    out[obase + 16 * (size_t)TH * TW] = acc1;
    out[obase + 32 * (size_t)TH * TW] = acc2;
}

extern "C" void kernel_launch(void* const* d_in, const int* in_sizes, int n_in,
                              void* d_out, int out_size, void* d_ws, size_t ws_size,
                              hipStream_t stream) {
    const float* tp = (const float*)d_in[0];
    const float* fl = (const float*)d_in[1];
    const float* fr = (const float*)d_in[2];
    float* out = (float*)d_out;

    dim3 grid(NH, NB);   // (512, 4)
    dim3 block(960);     // 15 waves, thread u == column X
    tile_warp_kernel<<<grid, block, 0, stream>>>(tp, fl, fr, out);
}